// Round 3
// baseline (309.240 us; speedup 1.0000x reference)
//
#include <hip/hip_runtime.h>
#include <cstdint>

#define HSZ 32
#define TSTEPS 256
#define ISZ 6

// sigmoid(x) = 1/(1+e^-x); tanh(x) = 2*sigmoid(2x)-1. Native v_exp/v_rcp.
__device__ __forceinline__ float fast_sigmoid(float x) {
    return __builtin_amdgcn_rcpf(1.0f + __expf(-x));
}
__device__ __forceinline__ float fast_tanh(float x) {
    return 2.0f * __builtin_amdgcn_rcpf(1.0f + __expf(-2.0f * x)) - 1.0f;
}

// Mapping: block = 256 threads = 4 waves; each wave handles 2 batch elements
// (lanes 0-31 -> elem A, lanes 32-63 -> elem B); lane j = hidden unit j.
// Each lane keeps its 4 gate rows of W_hh/W_ih in VGPRs (~155 regs), h/c in
// regs; h is broadcast per step via LDS (1 ds_write + 8 broadcast ds_read_b128,
// wave-synchronous, no __syncthreads in the T-loop).
__global__ __launch_bounds__(256, 2) void lstm_fused(
    const float* __restrict__ x,
    const float* __restrict__ W_ih,
    const float* __restrict__ W_hh,
    const float* __restrict__ b_ih,
    const float* __restrict__ b_hh,
    const float* __restrict__ W1,
    const float* __restrict__ b1,
    const float* __restrict__ W2,
    const float* __restrict__ b2,
    float* __restrict__ out)
{
    __shared__ __align__(16) float hbuf[4][2][HSZ];
    __shared__ float w1s[64 * 33];   // stride 33: conflict-free MLP reads
    __shared__ float b1s[64];
    __shared__ float w2s[64];

    const int tid  = threadIdx.x;
    const int wave = tid >> 6;
    const int lane = tid & 63;
    const int half = (lane >> 5) & 1;
    const int j    = lane & 31;

    // Stage MLP weights (blockwide, once).
    for (int idx = tid; idx < 64 * HSZ; idx += 256) {
        const int u = idx >> 5, k = idx & 31;
        w1s[u * 33 + k] = W1[idx];
    }
    if (tid < 64) { b1s[tid] = b1[tid]; w2s[tid] = W2[tid]; }
    __syncthreads();

    const int elem = blockIdx.x * 8 + wave * 2 + half;

    // Per-lane weight rows (gate order: i, f, g, o -> row = q*32 + j).
    float Wih[4][ISZ];
    float Whh[4][HSZ];
    float bias[4];
    #pragma unroll
    for (int q = 0; q < 4; ++q) {
        const int row = q * HSZ + j;
        #pragma unroll
        for (int k = 0; k < ISZ; ++k) Wih[q][k] = W_ih[row * ISZ + k];
        #pragma unroll
        for (int k = 0; k < HSZ; ++k) Whh[q][k] = W_hh[row * HSZ + k];
        bias[q] = b_ih[row] + b_hh[row];
    }

    float h = 0.0f, c = 0.0f;
    const float* xp = x + (size_t)elem * (TSTEPS * ISZ);

    // x prefetch (8B-aligned: step offset is a 24B multiple).
    float2 xc0 = *(const float2*)(xp + 0);
    float2 xc1 = *(const float2*)(xp + 2);
    float2 xc2 = *(const float2*)(xp + 4);

    float* hb = &hbuf[wave][half][0];

    for (int t = 0; t < TSTEPS; ++t) {
        // Prefetch next step's x (clamped at the tail; broadcast loads).
        const float* xn = xp + (t + 1 < TSTEPS ? (t + 1) : (TSTEPS - 1)) * ISZ;
        const float2 xn0 = *(const float2*)(xn + 0);
        const float2 xn1 = *(const float2*)(xn + 2);
        const float2 xn2 = *(const float2*)(xn + 4);

        // Broadcast h across the half-wave via LDS (wave-synchronous).
        hb[j] = h;
        __builtin_amdgcn_wave_barrier();

        float acc0 = bias[0], acc1 = bias[1], acc2 = bias[2], acc3 = bias[3];

        const float xv[ISZ] = {xc0.x, xc0.y, xc1.x, xc1.y, xc2.x, xc2.y};
        #pragma unroll
        for (int k = 0; k < ISZ; ++k) {
            acc0 = fmaf(Wih[0][k], xv[k], acc0);
            acc1 = fmaf(Wih[1][k], xv[k], acc1);
            acc2 = fmaf(Wih[2][k], xv[k], acc2);
            acc3 = fmaf(Wih[3][k], xv[k], acc3);
        }

        #pragma unroll
        for (int r = 0; r < 8; ++r) {
            const float4 hv = *(const float4*)(hb + r * 4);
            const float hk[4] = {hv.x, hv.y, hv.z, hv.w};
            #pragma unroll
            for (int m = 0; m < 4; ++m) {
                acc0 = fmaf(Whh[0][4 * r + m], hk[m], acc0);
                acc1 = fmaf(Whh[1][4 * r + m], hk[m], acc1);
                acc2 = fmaf(Whh[2][4 * r + m], hk[m], acc2);
                acc3 = fmaf(Whh[3][4 * r + m], hk[m], acc3);
            }
        }

        const float ig = fast_sigmoid(acc0);
        const float fg = fast_sigmoid(acc1);
        const float gg = fast_tanh(acc2);
        const float og = fast_sigmoid(acc3);
        c = fmaf(fg, c, ig * gg);
        h = og * fast_tanh(c);

        xc0 = xn0; xc1 = xn1; xc2 = xn2;
    }

    // Publish final h, then the MLP head: lane u (0..63) computes hidden unit u
    // for each of the wave's 2 elements; wave-reduce for the final dot.
    hb[j] = h;
    __builtin_amdgcn_wave_barrier();

    const float b2v = b2[0];
    #pragma unroll
    for (int e = 0; e < 2; ++e) {
        const float* hh = &hbuf[wave][e][0];
        float a = b1s[lane];
        #pragma unroll
        for (int k = 0; k < HSZ; ++k) a = fmaf(w1s[lane * 33 + k], hh[k], a);
        a = fmaxf(a, 0.0f) * w2s[lane];
        #pragma unroll
        for (int off = 32; off > 0; off >>= 1) a += __shfl_xor(a, off, 64);
        if (lane == 0) out[blockIdx.x * 8 + wave * 2 + e] = a + b2v;
    }
}

extern "C" void kernel_launch(void* const* d_in, const int* in_sizes, int n_in,
                              void* d_out, int out_size, void* d_ws, size_t ws_size,
                              hipStream_t stream) {
    const float* x    = (const float*)d_in[0];
    const float* W_ih = (const float*)d_in[1];
    const float* W_hh = (const float*)d_in[2];
    const float* b_ih = (const float*)d_in[3];
    const float* b_hh = (const float*)d_in[4];
    const float* W1   = (const float*)d_in[5];
    const float* b1   = (const float*)d_in[6];
    const float* W2   = (const float*)d_in[7];
    const float* b2   = (const float*)d_in[8];
    float* out = (float*)d_out;

    const int B = in_sizes[0] / (TSTEPS * ISZ);   // 8192
    const int grid = B / 8;                       // 8 elements per 256-thread block

    lstm_fused<<<grid, 256, 0, stream>>>(x, W_ih, W_hh, b_ih, b_hh,
                                         W1, b1, W2, b2, out);
}